// Round 1
// baseline (501.068 us; speedup 1.0000x reference)
//
#include <hip/hip_runtime.h>

#define HH 2048
#define WW 2048
#define RAD 8
#define TILE 1024
#define LW (TILE + 2*RAD)          // 1040
#define SW(p) ((p) + ((p) >> 3))   // LDS pad-swizzle: breaks stride-4-elem bank conflicts
#define CHK 32                     // rows per thread in vertical kernels

__device__ __forceinline__ void add4(float4& a, const float4 b){ a.x+=b.x; a.y+=b.y; a.z+=b.z; a.w+=b.w; }
__device__ __forceinline__ void sub4(float4& a, const float4 b){ a.x-=b.x; a.y-=b.y; a.z-=b.z; a.w-=b.w; }

// K1: channel-reduce x,y -> (Sx,Sy,Sxy,Sxx), horizontal clipped window-17 sum, write interleaved float4 T
__global__ __launch_bounds__(256) void k_hsum4(const float* __restrict__ x,
                                               const float* __restrict__ y,
                                               float4* __restrict__ T) {
  __shared__ float4 s[SW(LW - 1) + 1];
  const int row = blockIdx.x;
  const int c0  = blockIdx.y * TILE;
  const size_t cs = (size_t)HH * WW;
  const float* xr = x + (size_t)row * WW;
  const float* yr = y + (size_t)row * WW;
  for (int p = threadIdx.x; p < LW; p += 256) {
    int col = c0 - RAD + p;
    float4 v = make_float4(0.f, 0.f, 0.f, 0.f);
    if (col >= 0 && col < WW) {
      #pragma unroll
      for (int c = 0; c < 4; ++c) {
        float xv = xr[c * cs + col];
        float yv = yr[c * cs + col];
        v.x += xv; v.y += yv; v.z += xv * yv; v.w += xv * xv;
      }
    }
    s[SW(p)] = v;
  }
  __syncthreads();
  const int q0 = threadIdx.x * 4;
  const int j0 = c0 + q0;
  const int base = c0 - RAD;
  int lo = j0 - RAD; if (lo < 0) lo = 0;
  int hi = j0 + RAD; if (hi > WW - 1) hi = WW - 1;
  float4 acc = make_float4(0.f, 0.f, 0.f, 0.f);
  for (int col = lo; col <= hi; ++col) add4(acc, s[SW(col - base)]);
  float4* Tr = T + (size_t)row * WW;
  Tr[j0] = acc;
  #pragma unroll
  for (int q = 1; q < 4; ++q) {
    int j = j0 + q;
    if (j + RAD < WW)      add4(acc, s[SW(j + RAD - base)]);
    if (j - RAD - 1 >= 0)  sub4(acc, s[SW(j - RAD - 1 - base)]);
    Tr[j] = acc;
  }
}

// K2: vertical clipped window-17 sum on T (thread per column, sliding) + A/b' + mean_y_tmp(=By)
__global__ __launch_bounds__(256) void k_vsum4_ab(const float4* __restrict__ T,
                                                  float2* __restrict__ AB,
                                                  float* __restrict__ meanY) {
  const int j  = blockIdx.x * 256 + threadIdx.x;
  const int r0 = blockIdx.y * CHK;
  float4 acc = make_float4(0.f, 0.f, 0.f, 0.f);
  int lo = r0 - RAD; if (lo < 0) lo = 0;
  int hi = r0 + RAD; if (hi > HH - 1) hi = HH - 1;
  for (int i = lo; i <= hi; ++i) add4(acc, T[(size_t)i * WW + j]);
  int cl  = j - RAD; if (cl < 0) cl = 0;
  int chi = j + RAD; if (chi > WW - 1) chi = WW - 1;
  const float ncols = (float)(chi - cl + 1);
  for (int i = r0; i < r0 + CHK; ++i) {
    if (i > r0) {
      if (i + RAD < HH)     add4(acc, T[(size_t)(i + RAD) * WW + j]);
      if (i - RAD - 1 >= 0) sub4(acc, T[(size_t)(i - RAD - 1) * WW + j]);
    }
    int rl  = i - RAD; if (rl < 0) rl = 0;
    int rhi = i + RAD; if (rhi > HH - 1) rhi = HH - 1;
    float nrows = (float)(rhi - rl + 1);
    float invN = 1.0f / (4.0f * nrows * ncols);
    float mx = acc.x * invN, my = acc.y * invN;
    float A  = (acc.z * invN - mx * my) / (acc.w * invN - mx * mx + 1e-2f);
    float bp = my - A * mx;
    size_t idx = (size_t)i * WW + j;
    AB[idx] = make_float2(A, bp);
    meanY[idx] = acc.y;
  }
}

// K3: horizontal window-17 sum on AB (float2) -> T2
__global__ __launch_bounds__(256) void k_hsum2(const float2* __restrict__ in,
                                               float2* __restrict__ T2) {
  __shared__ float2 s[SW(LW - 1) + 1];
  const int row = blockIdx.x;
  const int c0  = blockIdx.y * TILE;
  const float2* ir = in + (size_t)row * WW;
  for (int p = threadIdx.x; p < LW; p += 256) {
    int col = c0 - RAD + p;
    s[SW(p)] = (col >= 0 && col < WW) ? ir[col] : make_float2(0.f, 0.f);
  }
  __syncthreads();
  const int q0 = threadIdx.x * 4;
  const int j0 = c0 + q0;
  const int base = c0 - RAD;
  int lo = j0 - RAD; if (lo < 0) lo = 0;
  int hi = j0 + RAD; if (hi > WW - 1) hi = WW - 1;
  float2 acc = make_float2(0.f, 0.f);
  for (int col = lo; col <= hi; ++col) { float2 v = s[SW(col - base)]; acc.x += v.x; acc.y += v.y; }
  float2* Tr = T2 + (size_t)row * WW;
  Tr[j0] = acc;
  #pragma unroll
  for (int q = 1; q < 4; ++q) {
    int j = j0 + q;
    if (j + RAD < WW)     { float2 v = s[SW(j + RAD - base)];     acc.x += v.x; acc.y += v.y; }
    if (j - RAD - 1 >= 0) { float2 v = s[SW(j - RAD - 1 - base)]; acc.x -= v.x; acc.y -= v.y; }
    Tr[j] = acc;
  }
}

// K4: vertical window-17 sum on T2 + final combine: out = BA/N * x2 + Bb/N
__global__ __launch_bounds__(256) void k_vsum2_out(const float2* __restrict__ T2,
                                                   const float* __restrict__ x2,
                                                   float* __restrict__ out) {
  const int j  = blockIdx.x * 256 + threadIdx.x;
  const int r0 = blockIdx.y * CHK;
  float2 acc = make_float2(0.f, 0.f);
  int lo = r0 - RAD; if (lo < 0) lo = 0;
  int hi = r0 + RAD; if (hi > HH - 1) hi = HH - 1;
  for (int i = lo; i <= hi; ++i) { float2 v = T2[(size_t)i * WW + j]; acc.x += v.x; acc.y += v.y; }
  int cl  = j - RAD; if (cl < 0) cl = 0;
  int chi = j + RAD; if (chi > WW - 1) chi = WW - 1;
  const float ncols = (float)(chi - cl + 1);
  for (int i = r0; i < r0 + CHK; ++i) {
    if (i > r0) {
      if (i + RAD < HH)     { float2 v = T2[(size_t)(i + RAD) * WW + j]; acc.x += v.x; acc.y += v.y; }
      if (i - RAD - 1 >= 0) { float2 v = T2[(size_t)(i - RAD - 1) * WW + j]; acc.x -= v.x; acc.y -= v.y; }
    }
    int rl  = i - RAD; if (rl < 0) rl = 0;
    int rhi = i + RAD; if (rhi > HH - 1) rhi = HH - 1;
    float nrows = (float)(rhi - rl + 1);
    float invN = 1.0f / (4.0f * nrows * ncols);
    size_t idx = (size_t)i * WW + j;
    out[idx] = acc.x * invN * x2[idx] + acc.y * invN;
  }
}

extern "C" void kernel_launch(void* const* d_in, const int* in_sizes, int n_in,
                              void* d_out, int out_size, void* d_ws, size_t ws_size,
                              hipStream_t stream) {
  const float* x = (const float*)d_in[0];
  const float* y = (const float*)d_in[1];
  float* out = (float*)d_out;
  const size_t HWsz = (size_t)HH * WW;          // 4,194,304
  float* ws = (float*)d_ws;
  float4* T4 = (float4*)ws;                     // HW float4  (67.1 MB)
  float2* AB = (float2*)(ws + 4 * HWsz);        // HW float2  (33.5 MB)
  float2* T2 = (float2*)ws;                     // overlays T4 (dead by K3)

  for (int b = 0; b < 2; ++b) {
    const float* xb = x + (size_t)b * 4 * HWsz;
    const float* yb = y + (size_t)b * 4 * HWsz;
    float* outb   = out + (size_t)b * HWsz;                 // output 0 region
    float* meanYb = out + 2 * HWsz + (size_t)b * HWsz;      // output 1 region

    hipLaunchKernelGGL(k_hsum4,    dim3(HH, WW / TILE), dim3(256), 0, stream, xb, yb, T4);
    hipLaunchKernelGGL(k_vsum4_ab, dim3(WW / 256, HH / CHK), dim3(256), 0, stream, T4, AB, meanYb);
    hipLaunchKernelGGL(k_hsum2,    dim3(HH, WW / TILE), dim3(256), 0, stream, AB, T2);
    hipLaunchKernelGGL(k_vsum2_out, dim3(WW / 256, HH / CHK), dim3(256), 0, stream, T2, xb + 2 * HWsz, outb);
  }
}

// Round 2
// 436.831 us; speedup vs baseline: 1.1471x; 1.1471x over previous
//
#include <hip/hip_runtime.h>

#define HH 2048
#define WW 2048
#define RAD 8
#define NT 192            // threads per block (3 waves)
#define OUTC 176          // output columns per block (NT - 2*RAD)
#define RSEG 98           // rows per block segment
#define NBX 12            // ceil(2048/176)
#define NBY 21            // ceil(2048/98)
#define WIN 17            // window = 2*RAD+1

__device__ __forceinline__ void add4(float4& a, const float4 b){ a.x+=b.x; a.y+=b.y; a.z+=b.z; a.w+=b.w; }
__device__ __forceinline__ void sub4(float4& a, const float4 b){ a.x-=b.x; a.y-=b.y; a.z-=b.z; a.w-=b.w; }

// Pass 1: x,y -> AB (A, b') + meanY.  Fused channel-reduce + vertical sliding
// window (LDS ring, thread-private slots) + horizontal 17-window (LDS row) + A/b math.
__global__ __launch_bounds__(NT, 2) void p1(const float* __restrict__ x,
                                            const float* __restrict__ y,
                                            float2* __restrict__ AB,
                                            float* __restrict__ meanY) {
  __shared__ float4 ring[WIN][NT];   // 52224 B
  __shared__ float4 vbuf[2][NT];     //  6144 B  (58368 total < 64KB)
  const int tid = threadIdx.x;
  const size_t cs = (size_t)HH * WW;
  const int bz = blockIdx.z;
  const float* xb = x + (size_t)bz * 4 * cs;
  const float* yb = y + (size_t)bz * 4 * cs;
  float2* ABb = AB + (size_t)bz * cs;
  float*  mYb = meanY + (size_t)bz * cs;
  const int col = blockIdx.x * OUTC + tid - RAD;
  const bool colok = (col >= 0 && col < WW);
  const int r0 = blockIdx.y * RSEG;

  auto load_s = [&](int row) -> float4 {
    float4 v = make_float4(0.f, 0.f, 0.f, 0.f);
    if (row >= 0 && row < HH && colok) {
      size_t o = (size_t)row * WW + col;
      float x0 = xb[o], x1 = xb[o + cs], x2 = xb[o + 2*cs], x3 = xb[o + 3*cs];
      float y0 = yb[o], y1 = yb[o + cs], y2 = yb[o + 2*cs], y3 = yb[o + 3*cs];
      v.x = (x0 + x1) + (x2 + x3);
      v.y = (y0 + y1) + (y2 + y3);
      v.z = x0*y0 + x1*y1 + x2*y2 + x3*y3;
      v.w = x0*x0 + x1*x1 + x2*x2 + x3*x3;
    }
    return v;
  };

  // warm-up: V = sum of rows [r0-8, r0+8] (out-of-range rows contribute zeros)
  float4 V = make_float4(0.f, 0.f, 0.f, 0.f);
  #pragma unroll
  for (int k = 0; k < WIN; ++k) {
    float4 s = load_s(r0 - RAD + k);
    ring[k][tid] = s;
    add4(V, s);
  }

  int sl = 0;
  const int tmax = (HH - r0 < RSEG) ? (HH - r0) : RSEG;
  for (int t = 0; t < tmax; ++t) {
    const int i = r0 + t;
    const int par = t & 1;
    vbuf[par][tid] = V;
    __syncthreads();
    float4 spre = load_s(i + RAD + 1);   // prefetch next row; latency hides under window phase
    if (tid >= RAD && tid < RAD + OUTC && col < WW) {
      float4 h = make_float4(0.f, 0.f, 0.f, 0.f);
      #pragma unroll
      for (int k = 0; k < WIN; ++k) add4(h, vbuf[par][tid - RAD + k]);
      int cl = col - RAD; if (cl < 0) cl = 0;
      int ch = col + RAD; if (ch > WW - 1) ch = WW - 1;
      int rl = i - RAD;   if (rl < 0) rl = 0;
      int rh = i + RAD;   if (rh > HH - 1) rh = HH - 1;
      float invN = 1.0f / (4.0f * (float)((ch - cl + 1) * (rh - rl + 1)));
      float mx = h.x * invN, my = h.y * invN;
      float A  = (h.z * invN - mx * my) / (h.w * invN - mx * mx + 1e-2f);
      float bp = my - A * mx;
      size_t idx = (size_t)i * WW + col;
      ABb[idx] = make_float2(A, bp);
      mYb[idx] = h.y;                    // mean_y_tmp = box_filter(raw y) = h.y
    }
    // slide V to row i+1: remove row i-8, add row i+9 (ring slot is thread-private)
    float4 sold = ring[sl][tid];
    sub4(V, sold);
    add4(V, spre);
    ring[sl][tid] = spre;
    sl = (sl == WIN - 1) ? 0 : sl + 1;
  }
}

// Pass 2: AB -> out = boxsum(A)/N * x2 + boxsum(b')/N. Same structure on float2.
__global__ __launch_bounds__(NT, 3) void p2(const float2* __restrict__ AB,
                                            const float* __restrict__ x,
                                            float* __restrict__ out) {
  __shared__ float2 ring[WIN][NT];   // 26112 B
  __shared__ float2 vbuf[2][NT];     //  3072 B
  const int tid = threadIdx.x;
  const size_t cs = (size_t)HH * WW;
  const int bz = blockIdx.z;
  const float2* ABb = AB + (size_t)bz * cs;
  const float*  x2b = x + (size_t)bz * 4 * cs + 2 * cs;   // channel c_x/2 = 2
  float* outb = out + (size_t)bz * cs;
  const int col = blockIdx.x * OUTC + tid - RAD;
  const bool colok = (col >= 0 && col < WW);
  const int r0 = blockIdx.y * RSEG;

  auto load_s = [&](int row) -> float2 {
    float2 v = make_float2(0.f, 0.f);
    if (row >= 0 && row < HH && colok) v = ABb[(size_t)row * WW + col];
    return v;
  };

  float2 V = make_float2(0.f, 0.f);
  #pragma unroll
  for (int k = 0; k < WIN; ++k) {
    float2 s = load_s(r0 - RAD + k);
    ring[k][tid] = s;
    V.x += s.x; V.y += s.y;
  }

  int sl = 0;
  const int tmax = (HH - r0 < RSEG) ? (HH - r0) : RSEG;
  for (int t = 0; t < tmax; ++t) {
    const int i = r0 + t;
    const int par = t & 1;
    vbuf[par][tid] = V;
    __syncthreads();
    float2 spre = load_s(i + RAD + 1);
    if (tid >= RAD && tid < RAD + OUTC && col < WW) {
      float2 h = make_float2(0.f, 0.f);
      #pragma unroll
      for (int k = 0; k < WIN; ++k) { float2 v = vbuf[par][tid - RAD + k]; h.x += v.x; h.y += v.y; }
      int cl = col - RAD; if (cl < 0) cl = 0;
      int ch = col + RAD; if (ch > WW - 1) ch = WW - 1;
      int rl = i - RAD;   if (rl < 0) rl = 0;
      int rh = i + RAD;   if (rh > HH - 1) rh = HH - 1;
      float invN = 1.0f / (4.0f * (float)((ch - cl + 1) * (rh - rl + 1)));
      size_t idx = (size_t)i * WW + col;
      outb[idx] = h.x * invN * x2b[idx] + h.y * invN;
    }
    float2 sold = ring[sl][tid];
    V.x -= sold.x; V.y -= sold.y;
    V.x += spre.x; V.y += spre.y;
    ring[sl][tid] = spre;
    sl = (sl == WIN - 1) ? 0 : sl + 1;
  }
}

extern "C" void kernel_launch(void* const* d_in, const int* in_sizes, int n_in,
                              void* d_out, int out_size, void* d_ws, size_t ws_size,
                              hipStream_t stream) {
  const float* x = (const float*)d_in[0];
  const float* y = (const float*)d_in[1];
  float* out = (float*)d_out;
  const size_t cs = (size_t)HH * WW;
  float2* AB = (float2*)d_ws;   // 2 batches x 4.19M float2 = 67 MB of ws

  hipLaunchKernelGGL(p1, dim3(NBX, NBY, 2), dim3(NT), 0, stream, x, y, AB, out + 2 * cs);
  hipLaunchKernelGGL(p2, dim3(NBX, NBY, 2), dim3(NT), 0, stream, AB, x, out);
}

// Round 5
// 419.853 us; speedup vs baseline: 1.1934x; 1.0404x over previous
//
#include <hip/hip_runtime.h>

#define HH 2048
#define WW 2048
#define RAD 8
#define WIN 17
#define RSEG 51           // rows per wave segment (3 x 17 for static ring indexing)
#define NCG 43            // col groups of 48 outputs (ceil(2048/48))
#define NRS 41            // row segments (40*51=2040, last covers 8)
#define NTASK (NCG * NRS * 2)
#define NBLK ((NTASK + 3) / 4)

__device__ __forceinline__ float4 shfl4(float4 v, int s) {
  return make_float4(__shfl(v.x, s, 64), __shfl(v.y, s, 64),
                     __shfl(v.z, s, 64), __shfl(v.w, s, 64));
}
__device__ __forceinline__ float2 shfl2(float2 v, int s) {
  return make_float2(__shfl(v.x, s, 64), __shfl(v.y, s, 64));
}
__device__ __forceinline__ float4 a4(float4 a, float4 b) {
  return make_float4(a.x + b.x, a.y + b.y, a.z + b.z, a.w + b.w);
}
__device__ __forceinline__ float2 a2(float2 a, float2 b) {
  return make_float2(a.x + b.x, a.y + b.y);
}

// Pass 1: x,y -> AB(A,b') + meanY. Wave-autonomous: register ring for the
// vertical sliding 17-window, shuffle prefix-doubling for the horizontal one.
__global__ __launch_bounds__(256) void p1(const float* __restrict__ x,
                                          const float* __restrict__ y,
                                          float2* __restrict__ AB,
                                          float* __restrict__ meanY) {
  const int wid = (blockIdx.x << 2) + (threadIdx.x >> 6);
  if (wid >= NTASK) return;
  const int lane = threadIdx.x & 63;
  const int cg = wid % NCG;
  const int rem = wid / NCG;
  const int rs = rem % NRS;
  const int bz = rem / NRS;
  const size_t cs = (size_t)HH * WW;
  const float* xb = x + (size_t)bz * 4 * cs;
  const float* yb = y + (size_t)bz * 4 * cs;
  float2* ABb = AB + (size_t)bz * cs;
  float*  mYb = meanY + (size_t)bz * cs;
  const int col = cg * 48 + lane - RAD;
  const bool colok = (col >= 0 && col < WW);
  const bool emit = (lane >= RAD && lane < RAD + 48 && col < WW);
  const int r0 = rs * RSEG;
  const int sp1 = (lane + 1) & 63, sp2 = (lane + 2) & 63, sp4 = (lane + 4) & 63;
  const int sp8 = (lane + 8) & 63, sm8 = (lane - 8) & 63;
  int cl = col - RAD; if (cl < 0) cl = 0;
  int ch = col + RAD; if (ch > WW - 1) ch = WW - 1;
  const float inv4c = 0.25f / (float)(ch - cl + 1);

  auto load_s = [&](int row) -> float4 {
    float4 v = make_float4(0.f, 0.f, 0.f, 0.f);
    if (row >= 0 && row < HH && colok) {
      size_t o = (size_t)row * WW + col;
      float x0 = xb[o], x1 = xb[o + cs], x2 = xb[o + 2*cs], x3 = xb[o + 3*cs];
      float y0 = yb[o], y1 = yb[o + cs], y2 = yb[o + 2*cs], y3 = yb[o + 3*cs];
      v.x = (x0 + x1) + (x2 + x3);
      v.y = (y0 + y1) + (y2 + y3);
      v.z = x0*y0 + x1*y1 + x2*y2 + x3*y3;
      v.w = x0*x0 + x1*x1 + x2*x2 + x3*x3;
    }
    return v;
  };

  float4 ring[WIN];
  float4 V = make_float4(0.f, 0.f, 0.f, 0.f);
  #pragma unroll
  for (int k = 0; k < WIN; ++k) {
    float4 s = load_s(r0 - RAD + k);
    ring[k] = s;
    V = a4(V, s);
  }

  for (int tt = 0; tt < RSEG / WIN; ++tt) {
    #pragma unroll
    for (int u = 0; u < WIN; ++u) {
      const int i = r0 + tt * WIN + u;
      if (i >= HH) return;                 // wave-uniform tail exit (no barriers anywhere)
      float4 spre = load_s(i + RAD + 1);   // prefetch; consumed only at slide below
      float4 t1 = a4(V,  shfl4(V,  sp1));
      float4 t2 = a4(t1, shfl4(t1, sp2));
      float4 t4 = a4(t2, shfl4(t2, sp4));
      float4 t8 = a4(t4, shfl4(t4, sp8));
      float4 h  = a4(shfl4(t8, sm8), shfl4(V, sp8));   // 17-window sum
      if (emit) {
        int rl = i - RAD; if (rl < 0) rl = 0;
        int rh = i + RAD; if (rh > HH - 1) rh = HH - 1;
        float invN = inv4c / (float)(rh - rl + 1);
        float mx = h.x * invN, my = h.y * invN;
        float A  = (h.z * invN - mx * my) / (h.w * invN - mx * mx + 1e-2f);
        float bp = my - A * mx;
        size_t idx = (size_t)i * WW + col;
        ABb[idx] = make_float2(A, bp);
        mYb[idx] = h.y;                    // mean_y_tmp = boxsum(raw y)
      }
      V = a4(V, spre);
      V.x -= ring[u].x; V.y -= ring[u].y; V.z -= ring[u].z; V.w -= ring[u].w;
      ring[u] = spre;                      // static slot: u == t mod 17
    }
  }
}

// Pass 2: AB -> out = (boxsum(A)*x2 + boxsum(b'))/N. Same structure on float2.
__global__ __launch_bounds__(256) void p2(const float2* __restrict__ AB,
                                          const float* __restrict__ x,
                                          float* __restrict__ out) {
  const int wid = (blockIdx.x << 2) + (threadIdx.x >> 6);
  if (wid >= NTASK) return;
  const int lane = threadIdx.x & 63;
  const int cg = wid % NCG;
  const int rem = wid / NCG;
  const int rs = rem % NRS;
  const int bz = rem / NRS;
  const size_t cs = (size_t)HH * WW;
  const float2* ABb = AB + (size_t)bz * cs;
  const float*  x2b = x + (size_t)bz * 4 * cs + 2 * cs;  // channel c_x/2 = 2
  float* outb = out + (size_t)bz * cs;
  const int col = cg * 48 + lane - RAD;
  const bool colok = (col >= 0 && col < WW);
  const bool emit = (lane >= RAD && lane < RAD + 48 && col < WW);
  const int r0 = rs * RSEG;
  const int sp1 = (lane + 1) & 63, sp2 = (lane + 2) & 63, sp4 = (lane + 4) & 63;
  const int sp8 = (lane + 8) & 63, sm8 = (lane - 8) & 63;
  int cl = col - RAD; if (cl < 0) cl = 0;
  int ch = col + RAD; if (ch > WW - 1) ch = WW - 1;
  const float inv4c = 0.25f / (float)(ch - cl + 1);

  auto load_s = [&](int row) -> float2 {
    float2 v = make_float2(0.f, 0.f);
    if (row >= 0 && row < HH && colok) v = ABb[(size_t)row * WW + col];
    return v;
  };

  float2 ring[WIN];
  float2 V = make_float2(0.f, 0.f);
  #pragma unroll
  for (int k = 0; k < WIN; ++k) {
    float2 s = load_s(r0 - RAD + k);
    ring[k] = s;
    V = a2(V, s);
  }

  for (int tt = 0; tt < RSEG / WIN; ++tt) {
    #pragma unroll
    for (int u = 0; u < WIN; ++u) {
      const int i = r0 + tt * WIN + u;
      if (i >= HH) return;
      float2 spre = load_s(i + RAD + 1);
      const size_t idx = (size_t)i * WW + col;
      float xv = 0.f;
      if (emit) xv = x2b[idx];             // issue early; used after shuffle chain
      float2 t1 = a2(V,  shfl2(V,  sp1));
      float2 t2 = a2(t1, shfl2(t1, sp2));
      float2 t4 = a2(t2, shfl2(t2, sp4));
      float2 t8 = a2(t4, shfl2(t4, sp8));
      float2 h  = a2(shfl2(t8, sm8), shfl2(V, sp8));
      if (emit) {
        int rl = i - RAD; if (rl < 0) rl = 0;
        int rh = i + RAD; if (rh > HH - 1) rh = HH - 1;
        float invN = inv4c / (float)(rh - rl + 1);
        outb[idx] = (h.x * xv + h.y) * invN;
      }
      V = a2(V, spre);
      V.x -= ring[u].x; V.y -= ring[u].y;
      ring[u] = spre;
    }
  }
}

extern "C" void kernel_launch(void* const* d_in, const int* in_sizes, int n_in,
                              void* d_out, int out_size, void* d_ws, size_t ws_size,
                              hipStream_t stream) {
  const float* x = (const float*)d_in[0];
  const float* y = (const float*)d_in[1];
  float* out = (float*)d_out;
  const size_t cs = (size_t)HH * WW;
  float2* AB = (float2*)d_ws;   // 2 batches x 4.19M float2 = 67 MB of ws

  hipLaunchKernelGGL(p1, dim3(NBLK), dim3(256), 0, stream, x, y, AB, out + 2 * cs);
  hipLaunchKernelGGL(p2, dim3(NBLK), dim3(256), 0, stream, AB, x, out);
}

// Round 6
// 416.849 us; speedup vs baseline: 1.2020x; 1.0072x over previous
//
#include <hip/hip_runtime.h>

#define HH 2048
#define WW 2048
#define RAD 8
#define WIN 17
#define RSEG 34           // rows per wave segment (2 x 17, static ring indexing)
#define NCG 43            // col groups of 48 outputs (ceil(2048/48))
#define NRS 61            // row segments (60*34=2040, last covers 8)
#define NTASK (NCG * NRS * 2)
#define NBLK ((NTASK + 3) / 4)

__device__ __forceinline__ float4 shfl4(float4 v, int s) {
  return make_float4(__shfl(v.x, s, 64), __shfl(v.y, s, 64),
                     __shfl(v.z, s, 64), __shfl(v.w, s, 64));
}
__device__ __forceinline__ float2 shfl2(float2 v, int s) {
  return make_float2(__shfl(v.x, s, 64), __shfl(v.y, s, 64));
}
__device__ __forceinline__ float4 a4(float4 a, float4 b) {
  return make_float4(a.x + b.x, a.y + b.y, a.z + b.z, a.w + b.w);
}
__device__ __forceinline__ float2 a2(float2 a, float2 b) {
  return make_float2(a.x + b.x, a.y + b.y);
}

// Pass 1: x,y -> AB(A,b') + meanY. Wave-autonomous: register ring for the
// vertical sliding 17-window, shuffle prefix-doubling for the horizontal one.
// 2-deep global prefetch: load for row i+10 issued at iter i, consumed at i+1.
__global__ __launch_bounds__(256) void p1(const float* __restrict__ x,
                                          const float* __restrict__ y,
                                          float2* __restrict__ AB,
                                          float* __restrict__ meanY) {
  const int wid = (blockIdx.x << 2) + (threadIdx.x >> 6);
  if (wid >= NTASK) return;
  const int lane = threadIdx.x & 63;
  const int cg = wid % NCG;
  const int rem = wid / NCG;
  const int rs = rem % NRS;
  const int bz = rem / NRS;
  const size_t cs = (size_t)HH * WW;
  const float* xb = x + (size_t)bz * 4 * cs;
  const float* yb = y + (size_t)bz * 4 * cs;
  float2* ABb = AB + (size_t)bz * cs;
  float*  mYb = meanY + (size_t)bz * cs;
  const int col = cg * 48 + lane - RAD;
  const bool colok = (col >= 0 && col < WW);
  const bool emit = (lane >= RAD && lane < RAD + 48 && col < WW);
  const int r0 = rs * RSEG;
  const int sp1 = (lane + 1) & 63, sp2 = (lane + 2) & 63, sp4 = (lane + 4) & 63;
  const int sp8 = (lane + 8) & 63, sm8 = (lane - 8) & 63;
  int cl = col - RAD; if (cl < 0) cl = 0;
  int ch = col + RAD; if (ch > WW - 1) ch = WW - 1;
  const float inv4c = 0.25f / (float)(ch - cl + 1);

  auto load_s = [&](int row) -> float4 {
    float4 v = make_float4(0.f, 0.f, 0.f, 0.f);
    if (row >= 0 && row < HH && colok) {
      size_t o = (size_t)row * WW + col;
      float x0 = xb[o], x1 = xb[o + cs], x2 = xb[o + 2*cs], x3 = xb[o + 3*cs];
      float y0 = yb[o], y1 = yb[o + cs], y2 = yb[o + 2*cs], y3 = yb[o + 3*cs];
      v.x = (x0 + x1) + (x2 + x3);
      v.y = (y0 + y1) + (y2 + y3);
      v.z = x0*y0 + x1*y1 + x2*y2 + x3*y3;
      v.w = x0*x0 + x1*x1 + x2*x2 + x3*x3;
    }
    return v;
  };

  float4 ring[WIN];
  float4 V = make_float4(0.f, 0.f, 0.f, 0.f);
  #pragma unroll
  for (int k = 0; k < WIN; ++k) {
    float4 s = load_s(r0 - RAD + k);
    ring[k] = s;
    V = a4(V, s);
  }
  float4 sp = load_s(r0 + RAD + 1);      // row r0+9 in flight

  for (int tt = 0; tt < RSEG / WIN; ++tt) {
    #pragma unroll
    for (int u = 0; u < WIN; ++u) {
      const int i = r0 + tt * WIN + u;
      if (i >= HH) return;                 // wave-uniform tail exit (no barriers anywhere)
      float4 sn = load_s(i + RAD + 2);     // issue row i+10; consumed next iteration
      float4 t1 = a4(V,  shfl4(V,  sp1));
      float4 t2 = a4(t1, shfl4(t1, sp2));
      float4 t4 = a4(t2, shfl4(t2, sp4));
      float4 t8 = a4(t4, shfl4(t4, sp8));
      float4 h  = a4(shfl4(t8, sm8), shfl4(V, sp8));   // 17-window sum
      if (emit) {
        int rl = i - RAD; if (rl < 0) rl = 0;
        int rh = i + RAD; if (rh > HH - 1) rh = HH - 1;
        float invN = inv4c / (float)(rh - rl + 1);
        float mx = h.x * invN, my = h.y * invN;
        float A  = (h.z * invN - mx * my) / (h.w * invN - mx * mx + 1e-2f);
        float bp = my - A * mx;
        size_t idx = (size_t)i * WW + col;
        ABb[idx] = make_float2(A, bp);
        mYb[idx] = h.y;                    // mean_y_tmp = boxsum(raw y)
      }
      // slide V to row i+1: remove row i-8 (ring slot u), add row i+9 (sp)
      V = a4(V, sp);
      V.x -= ring[u].x; V.y -= ring[u].y; V.z -= ring[u].z; V.w -= ring[u].w;
      ring[u] = sp;                        // static slot: u == t mod 17
      sp = sn;
    }
  }
}

// Pass 2: AB -> out = (boxsum(A)*x2 + boxsum(b'))/N. Same structure on float2.
__global__ __launch_bounds__(256) void p2(const float2* __restrict__ AB,
                                          const float* __restrict__ x,
                                          float* __restrict__ out) {
  const int wid = (blockIdx.x << 2) + (threadIdx.x >> 6);
  if (wid >= NTASK) return;
  const int lane = threadIdx.x & 63;
  const int cg = wid % NCG;
  const int rem = wid / NCG;
  const int rs = rem % NRS;
  const int bz = rem / NRS;
  const size_t cs = (size_t)HH * WW;
  const float2* ABb = AB + (size_t)bz * cs;
  const float*  x2b = x + (size_t)bz * 4 * cs + 2 * cs;  // channel c_x/2 = 2
  float* outb = out + (size_t)bz * cs;
  const int col = cg * 48 + lane - RAD;
  const bool colok = (col >= 0 && col < WW);
  const bool emit = (lane >= RAD && lane < RAD + 48 && col < WW);
  const int r0 = rs * RSEG;
  const int sp1 = (lane + 1) & 63, sp2 = (lane + 2) & 63, sp4 = (lane + 4) & 63;
  const int sp8 = (lane + 8) & 63, sm8 = (lane - 8) & 63;
  int cl = col - RAD; if (cl < 0) cl = 0;
  int ch = col + RAD; if (ch > WW - 1) ch = WW - 1;
  const float inv4c = 0.25f / (float)(ch - cl + 1);

  auto load_s = [&](int row) -> float2 {
    float2 v = make_float2(0.f, 0.f);
    if (row >= 0 && row < HH && colok) v = ABb[(size_t)row * WW + col];
    return v;
  };

  float2 ring[WIN];
  float2 V = make_float2(0.f, 0.f);
  #pragma unroll
  for (int k = 0; k < WIN; ++k) {
    float2 s = load_s(r0 - RAD + k);
    ring[k] = s;
    V = a2(V, s);
  }
  float2 sp = load_s(r0 + RAD + 1);

  for (int tt = 0; tt < RSEG / WIN; ++tt) {
    #pragma unroll
    for (int u = 0; u < WIN; ++u) {
      const int i = r0 + tt * WIN + u;
      if (i >= HH) return;
      float2 sn = load_s(i + RAD + 2);
      const size_t idx = (size_t)i * WW + col;
      float xv = 0.f;
      if (emit) xv = x2b[idx];             // issue early; used after shuffle chain
      float2 t1 = a2(V,  shfl2(V,  sp1));
      float2 t2 = a2(t1, shfl2(t1, sp2));
      float2 t4 = a2(t2, shfl2(t2, sp4));
      float2 t8 = a2(t4, shfl2(t4, sp8));
      float2 h  = a2(shfl2(t8, sm8), shfl2(V, sp8));
      if (emit) {
        int rl = i - RAD; if (rl < 0) rl = 0;
        int rh = i + RAD; if (rh > HH - 1) rh = HH - 1;
        float invN = inv4c / (float)(rh - rl + 1);
        outb[idx] = (h.x * xv + h.y) * invN;
      }
      V = a2(V, sp);
      V.x -= ring[u].x; V.y -= ring[u].y;
      ring[u] = sp;
      sp = sn;
    }
  }
}

extern "C" void kernel_launch(void* const* d_in, const int* in_sizes, int n_in,
                              void* d_out, int out_size, void* d_ws, size_t ws_size,
                              hipStream_t stream) {
  const float* x = (const float*)d_in[0];
  const float* y = (const float*)d_in[1];
  float* out = (float*)d_out;
  const size_t cs = (size_t)HH * WW;
  float2* AB = (float2*)d_ws;   // 2 batches x 4.19M float2 = 67 MB of ws

  hipLaunchKernelGGL(p1, dim3(NBLK), dim3(256), 0, stream, x, y, AB, out + 2 * cs);
  hipLaunchKernelGGL(p2, dim3(NBLK), dim3(256), 0, stream, AB, x, out);
}